// Round 3
// baseline (263.404 us; speedup 1.0000x reference)
//
#include <hip/hip_runtime.h>
#include <hip/hip_bf16.h>
#include <stdint.h>
#include <stddef.h>

// B=2, S=2048, D=1024, H=16, C=64
typedef __bf16 bf16;
typedef __bf16 bf16x4 __attribute__((ext_vector_type(4)));
typedef __bf16 bf16x8 __attribute__((ext_vector_type(8)));
typedef float f32x4 __attribute__((ext_vector_type(4)));

#define DEV __device__ __forceinline__

// async global->LDS, 16B per lane; LDS dest is wave-uniform base + lane*16
DEV void async16(const bf16* g, bf16* l) {
    __builtin_amdgcn_global_load_lds(
        (const __attribute__((address_space(1))) void*)g,
        (__attribute__((address_space(3))) void*)l,
        16, 0, 0);
}

// pack two f32 -> two bf16 (truncation) in ONE v_perm_b32.
// Truncation bias cancels in P/l since l is computed from the same packed P.
DEV uint32_t pktrunc(float lo, float hi) {
    return __builtin_amdgcn_perm(__builtin_bit_cast(uint32_t, hi),
                                 __builtin_bit_cast(uint32_t, lo), 0x07060302u);
}

// ---------------- prep: x->bf16 convert (z=4) + 4 weight transposes (z=0..3) --

__global__ void prep(const float* __restrict__ x,
                     const float* __restrict__ Wq, const float* __restrict__ Wk,
                     const float* __restrict__ Wv, const float* __restrict__ Wo,
                     bf16* __restrict__ xb, bf16* __restrict__ WqkvT,
                     bf16* __restrict__ WoT) {
    __shared__ float t[32][33];
    if (blockIdx.z == 4) {
        const int bid = blockIdx.y * 32 + blockIdx.x;
#pragma unroll
        for (int i = 0; i < 4; ++i) {
            const int idx = ((bid * 4 + i) * 256 + threadIdx.x) * 4;
            const float4 v = *(const float4*)(x + idx);
            bf16 o4[4] = {(bf16)v.x, (bf16)v.y, (bf16)v.z, (bf16)v.w};
            *(uint2*)(xb + idx) = *(const uint2*)o4;
        }
        return;
    }
    const float* src;
    bf16* dst;
    float scale = 1.0f;
    switch (blockIdx.z) {
        case 0: src = Wq; dst = WqkvT; scale = 0.125f * 1.4426950408889634f; break;
        case 1: src = Wk; dst = WqkvT + 1024 * 1024; break;
        case 2: src = Wv; dst = WqkvT + 2 * 1024 * 1024; break;
        default: src = Wo; dst = WoT; break;
    }
    const int c0 = blockIdx.x * 32, r0 = blockIdx.y * 32;
    const int tx = threadIdx.x & 31, ty = threadIdx.x >> 5;  // 32x8
#pragma unroll
    for (int i = 0; i < 32; i += 8)
        t[ty + i][tx] = src[(size_t)(r0 + ty + i) * 1024 + c0 + tx];
    __syncthreads();
#pragma unroll
    for (int i = 0; i < 32; i += 8)
        dst[(size_t)(c0 + ty + i) * 1024 + r0 + tx] = (bf16)(t[tx][ty + i] * scale);
}

// ---------------- GEMM (TM=4): C[m][n] = sum_k A[m][k] * BT[n][k] ----------
// 128x128 tile, BK=64 as two BK=32 panels. If VTout != nullptr, tiles with
// n0 >= 2048 are stored TRANSPOSED to VTout[n-2048][m] (bf16) instead of C.

template <bool OUT_F32>
__global__ __launch_bounds__(256, 3) void gemm_bt(
    const bf16* __restrict__ A, const bf16* __restrict__ BT, void* __restrict__ Cout,
    int M, int N, int K, bf16* __restrict__ VTout) {
    __shared__ __attribute__((aligned(16))) bf16 As[2 * 128 * 32];
    __shared__ __attribute__((aligned(16))) bf16 Bs[2 * 128 * 32];
    const int tid = threadIdx.x;
    const int wid = tid >> 6;
    const int lane = tid & 63;
    const int quad = lane >> 4;
    const int l16 = lane & 15;
    const int wm = wid >> 1, wn = wid & 1;
    const int m0 = blockIdx.y * 128, n0 = blockIdx.x * 128;

    const int srow = wid * 32 + (lane >> 2);
    const int skcol = (lane & 3) * 8;
    const bf16* ag = A + (size_t)(m0 + srow) * K + skcol;
    const bf16* bg = BT + (size_t)(n0 + srow) * K + skcol;

    f32x4 acc[4][4];
#pragma unroll
    for (int i = 0; i < 4; ++i)
#pragma unroll
        for (int j = 0; j < 4; ++j) acc[i][j] = (f32x4){0.f, 0.f, 0.f, 0.f};

    for (int k0 = 0; k0 < K; k0 += 64) {
#pragma unroll
        for (int p = 0; p < 2; ++p) {
            async16(ag + k0 + p * 32, &As[p * 4096 + (wid * 32) * 32]);
            async16(ag + (size_t)16 * K + k0 + p * 32, &As[p * 4096 + (wid * 32 + 16) * 32]);
            async16(bg + k0 + p * 32, &Bs[p * 4096 + (wid * 32) * 32]);
            async16(bg + (size_t)16 * K + k0 + p * 32, &Bs[p * 4096 + (wid * 32 + 16) * 32]);
        }
        __syncthreads();

#pragma unroll
        for (int ks = 0; ks < 2; ++ks) {
            bf16x8 af[4], bfr[4];
#pragma unroll
            for (int mi = 0; mi < 4; ++mi)
                af[mi] = *(const bf16x8*)&As[ks * 4096 + (wm * 64 + mi * 16 + l16) * 32 + quad * 8];
#pragma unroll
            for (int ni = 0; ni < 4; ++ni)
                bfr[ni] = *(const bf16x8*)&Bs[ks * 4096 + (wn * 64 + ni * 16 + l16) * 32 + quad * 8];
#pragma unroll
            for (int mi = 0; mi < 4; ++mi)
#pragma unroll
                for (int ni = 0; ni < 4; ++ni)
                    acc[mi][ni] = __builtin_amdgcn_mfma_f32_16x16x32_bf16(
                        af[mi], bfr[ni], acc[mi][ni], 0, 0, 0);
        }
        __syncthreads();
    }

    if (VTout && n0 >= 2048) {
        // store transposed: VT[n-2048][m], pack 4 consecutive m (r) as 8B
#pragma unroll
        for (int mi = 0; mi < 4; ++mi)
#pragma unroll
            for (int ni = 0; ni < 4; ++ni) {
                bf16 pk[4] = {(bf16)acc[mi][ni][0], (bf16)acc[mi][ni][1],
                              (bf16)acc[mi][ni][2], (bf16)acc[mi][ni][3]};
                *(uint2*)&VTout[(size_t)(n0 - 2048 + wn * 64 + ni * 16 + l16) * 4096 +
                                (m0 + wm * 64 + mi * 16 + quad * 4)] = *(const uint2*)pk;
            }
        return;
    }
    if (OUT_F32) {
        float* C = (float*)Cout;
#pragma unroll
        for (int mi = 0; mi < 4; ++mi)
#pragma unroll
            for (int ni = 0; ni < 4; ++ni)
#pragma unroll
                for (int r = 0; r < 4; ++r)
                    C[(size_t)(m0 + wm * 64 + mi * 16 + quad * 4 + r) * N +
                      (n0 + wn * 64 + ni * 16 + l16)] = acc[mi][ni][r];
    } else {
        bf16* C = (bf16*)Cout;
#pragma unroll
        for (int mi = 0; mi < 4; ++mi)
#pragma unroll
            for (int ni = 0; ni < 4; ++ni)
#pragma unroll
                for (int r = 0; r < 4; ++r)
                    C[(size_t)(m0 + wm * 64 + mi * 16 + quad * 4 + r) * N +
                      (n0 + wn * 64 + ni * 16 + l16)] = (bf16)acc[mi][ni][r];
    }
}

// ---------------- GEMM (TM=2): 64x128 tile, fp32 out --------------------

__global__ __launch_bounds__(256, 4) void gemm_tm2(
    const bf16* __restrict__ A, const bf16* __restrict__ BT, float* __restrict__ C,
    int M, int N, int K) {
    __shared__ __attribute__((aligned(16))) bf16 As[2 * 64 * 32];
    __shared__ __attribute__((aligned(16))) bf16 Bs[2 * 128 * 32];
    const int tid = threadIdx.x;
    const int wid = tid >> 6;
    const int lane = tid & 63;
    const int quad = lane >> 4;
    const int l16 = lane & 15;
    const int wm = wid >> 1, wn = wid & 1;
    const int m0 = blockIdx.y * 64, n0 = blockIdx.x * 128;

    const int srowA = wid * 16 + (lane >> 2);
    const int srowB = wid * 32 + (lane >> 2);
    const int skcol = (lane & 3) * 8;
    const bf16* ag = A + (size_t)(m0 + srowA) * K + skcol;
    const bf16* bg = BT + (size_t)(n0 + srowB) * K + skcol;

    f32x4 acc[2][4];
#pragma unroll
    for (int i = 0; i < 2; ++i)
#pragma unroll
        for (int j = 0; j < 4; ++j) acc[i][j] = (f32x4){0.f, 0.f, 0.f, 0.f};

    for (int k0 = 0; k0 < K; k0 += 64) {
#pragma unroll
        for (int p = 0; p < 2; ++p) {
            async16(ag + k0 + p * 32, &As[p * 2048 + (wid * 16) * 32]);
            async16(bg + k0 + p * 32, &Bs[p * 4096 + (wid * 32) * 32]);
            async16(bg + (size_t)16 * K + k0 + p * 32, &Bs[p * 4096 + (wid * 32 + 16) * 32]);
        }
        __syncthreads();

#pragma unroll
        for (int ks = 0; ks < 2; ++ks) {
            bf16x8 af[2], bfr[4];
#pragma unroll
            for (int mi = 0; mi < 2; ++mi)
                af[mi] = *(const bf16x8*)&As[ks * 2048 + (wm * 32 + mi * 16 + l16) * 32 + quad * 8];
#pragma unroll
            for (int ni = 0; ni < 4; ++ni)
                bfr[ni] = *(const bf16x8*)&Bs[ks * 4096 + (wn * 64 + ni * 16 + l16) * 32 + quad * 8];
#pragma unroll
            for (int mi = 0; mi < 2; ++mi)
#pragma unroll
                for (int ni = 0; ni < 4; ++ni)
                    acc[mi][ni] = __builtin_amdgcn_mfma_f32_16x16x32_bf16(
                        af[mi], bfr[ni], acc[mi][ni], 0, 0, 0);
        }
        __syncthreads();
    }

#pragma unroll
    for (int mi = 0; mi < 2; ++mi)
#pragma unroll
        for (int ni = 0; ni < 4; ++ni)
#pragma unroll
            for (int r = 0; r < 4; ++r)
                C[(size_t)(m0 + wm * 32 + mi * 16 + quad * 4 + r) * N +
                  (n0 + wn * 64 + ni * 16 + l16)] = acc[mi][ni][r];
}

// ---------------- flash attention (v14: V direct from L2, 1 barrier/iter) --
// v13 post-mortem: 2x occupancy, 0 speedup -> throughput-bound on the LDS
// pipe (224 LDS wave-insts/block-iter ~ 31us of 48.7). v14 cuts LDS insts
// 224 -> 80: V fragments load straight from VT (L2-resident per XCD; lo+hi
// share one 64B line), Vs staging deleted; freed LDS pays for a DOUBLE-
// BUFFERED Ks -> one barrier per iter, waves skew and overlap.

__global__ __launch_bounds__(512, 4) void flash_attn(
    const bf16* __restrict__ QKV, const bf16* __restrict__ VT, bf16* __restrict__ att) {
    constexpr int LDK = 72;        // Ks stride: frag-read banks conflict-clean
    constexpr int KBUF = 128 * LDK * 2;  // 18432 B per buffer
    __shared__ __attribute__((aligned(16))) char smem[2 * KBUF + 1024];
    float* Osc = (float*)smem;                   // epilogue alias: 4 x 8 KB
    float* Lred = (float*)(smem + 2 * KBUF);     // [8][32] floats

    const int tid = threadIdx.x, wid = tid >> 6, lane = tid & 63;
    const int quad = lane >> 4, l16 = lane & 15;
    const int qh = wid >> 1, kh = wid & 1;        // qh 0..3 (32 q-rows), kh 0..1
    const int bh = blockIdx.x, qt = blockIdx.y;   // XCD = bh % 8 (L2-local K/V)
    const int b = bh >> 4, h = bh & 15;
    const int q0 = qt * 128;

    // ---- Q B-frags (resident): B[k=quad*8+j][n=l16] = Q[q][c] ----
    bf16x8 qf[2][2];
    {
        const bf16* qbase = QKV + (size_t)(b * 2048 + q0 + qh * 32 + l16) * 3072 + h * 64 + quad * 8;
#pragma unroll
        for (int mi = 0; mi < 2; ++mi)
#pragma unroll
            for (int ks = 0; ks < 2; ++ks)
                qf[mi][ks] = *(const bf16x8*)(qbase + (size_t)mi * 16 * 3072 + ks * 32);
    }

    // K staging geometry (coalesced, 512 threads): 128 rows x 128 B as 2
    // passes of 64 rows (8 lanes/row x 16 B)
    const int krow = tid >> 3, kcol = (tid & 7) * 8;  // krow 0..63
    const bf16* kg = QKV + (size_t)(b * 2048 + krow) * 3072 + 1024 + h * 64 + kcol;
    // V direct-load base: lane (l16, quad) reads VT[h*64+ct*16+l16][... + quad*4]
    const bf16* vg = VT + (size_t)(h * 64 + l16) * 4096 + b * 2048 + quad * 4;

    bf16x8 kr[2];
#pragma unroll
    for (int p = 0; p < 2; ++p)
        kr[p] = *(const bf16x8*)(kg + (size_t)(64 * p) * 3072);

    const bf16 one = (bf16)1.0f;
    const bf16x8 onesf = (bf16x8){one, one, one, one, one, one, one, one};

    f32x4 o[2][4];
    f32x4 ls[2];
#pragma unroll
    for (int mi = 0; mi < 2; ++mi) {
        ls[mi] = (f32x4){0.f, 0.f, 0.f, 0.f};
#pragma unroll
        for (int ct = 0; ct < 4; ++ct) o[mi][ct] = (f32x4){0.f, 0.f, 0.f, 0.f};
    }

    for (int it = 0; it < 16; ++it) {
        bf16* Ks = (bf16*)(smem + (it & 1) * KBUF);

        // ---- stage prefetched K regs -> LDS (double buffer: 1 barrier) ----
#pragma unroll
        for (int p = 0; p < 2; ++p)
            *(bf16x8*)&Ks[(64 * p + krow) * LDK + kcol] = kr[p];
        __syncthreads();

        // ---- prefetch next iter's K (hidden behind compute phase) ----
        if (it < 15) {
            const size_t ko = (size_t)(it + 1) * 128;
#pragma unroll
            for (int p = 0; p < 2; ++p)
                kr[p] = *(const bf16x8*)(kg + (ko + 64 * p) * 3072);
        }

        // ---- compute: wave's 64 keys as 2 pairs of 16-key groups ----
#pragma unroll
        for (int pr = 0; pr < 2; ++pr) {
            const int kb = kh * 64 + pr * 32;  // pair base (rel key)
            // V fragments straight from L2 (issued first, consumed after
            // QK+exp ~400cyc later; lo+hi are in the same 64B line)
            bf16x4 vlo[4], vhi[4];
#pragma unroll
            for (int ct = 0; ct < 4; ++ct) {
                const bf16* vp = vg + (size_t)(ct * 16) * 4096 + it * 128 + kb;
                vlo[ct] = *(const bf16x4*)vp;
                vhi[ct] = *(const bf16x4*)(vp + 16);
            }
            const bf16x8 kfA0 = *(const bf16x8*)&Ks[(kb + l16) * LDK + quad * 8];
            const bf16x8 kfA1 = *(const bf16x8*)&Ks[(kb + l16) * LDK + 32 + quad * 8];
            const bf16x8 kfB0 = *(const bf16x8*)&Ks[(kb + 16 + l16) * LDK + quad * 8];
            const bf16x8 kfB1 = *(const bf16x8*)&Ks[(kb + 16 + l16) * LDK + 32 + quad * 8];
#pragma unroll
            for (int mi = 0; mi < 2; ++mi) {
                f32x4 sA = (f32x4){0.f, 0.f, 0.f, 0.f};
                f32x4 sB = (f32x4){0.f, 0.f, 0.f, 0.f};
                sA = __builtin_amdgcn_mfma_f32_16x16x32_bf16(kfA0, qf[mi][0], sA, 0, 0, 0);
                sA = __builtin_amdgcn_mfma_f32_16x16x32_bf16(kfA1, qf[mi][1], sA, 0, 0, 0);
                sB = __builtin_amdgcn_mfma_f32_16x16x32_bf16(kfB0, qf[mi][0], sB, 0, 0, 0);
                sB = __builtin_amdgcn_mfma_f32_16x16x32_bf16(kfB1, qf[mi][1], sB, 0, 0, 0);

                const float pa0 = __builtin_amdgcn_exp2f(sA[0]);
                const float pa1 = __builtin_amdgcn_exp2f(sA[1]);
                const float pa2 = __builtin_amdgcn_exp2f(sA[2]);
                const float pa3 = __builtin_amdgcn_exp2f(sA[3]);
                const float pb0 = __builtin_amdgcn_exp2f(sB[0]);
                const float pb1 = __builtin_amdgcn_exp2f(sB[1]);
                const float pb2 = __builtin_amdgcn_exp2f(sB[2]);
                const float pb3 = __builtin_amdgcn_exp2f(sB[3]);

                // P A-frag via truncation pack (4 v_perm); lane = P[q=l16][j0..7]
                union { uint32_t u[4]; bf16x8 v; } pu;
                pu.u[0] = pktrunc(pa0, pa1);
                pu.u[1] = pktrunc(pa2, pa3);
                pu.u[2] = pktrunc(pb0, pb1);
                pu.u[3] = pktrunc(pb2, pb3);
                const bf16x8 pf = pu.v;
#pragma unroll
                for (int ct = 0; ct < 4; ++ct) {
                    const bf16x8 vf = (bf16x8){vlo[ct][0], vlo[ct][1], vlo[ct][2], vlo[ct][3],
                                               vhi[ct][0], vhi[ct][1], vhi[ct][2], vhi[ct][3]};
                    o[mi][ct] = __builtin_amdgcn_mfma_f32_16x16x32_bf16(pf, vf, o[mi][ct], 0, 0, 0);
                }
                // l-sum on the matrix pipe: D[q][*] = sum_k pf (all cols equal)
                ls[mi] = __builtin_amdgcn_mfma_f32_16x16x32_bf16(pf, onesf, ls[mi], 0, 0, 0);
            }
        }
        // no trailing barrier: next iter writes the other Ks buffer
    }
    __syncthreads();  // Osc aliases Ks buffers: wait for all compute

    // ---- epilogue: publish l (q = mi*16+quad*4+r), cross-wave O reduce ----
    if (l16 == 0) {
#pragma unroll
        for (int mi = 0; mi < 2; ++mi)
#pragma unroll
            for (int r = 0; r < 4; ++r)
                Lred[wid * 32 + mi * 16 + quad * 4 + r] = ls[mi][r];
    }
    if (kh == 1) {
        float* dst = Osc + qh * 2048;
#pragma unroll
        for (int mi = 0; mi < 2; ++mi)
#pragma unroll
            for (int ct = 0; ct < 4; ++ct)
                *(f32x4*)(dst + (mi * 4 + ct) * 256 + lane * 4) = o[mi][ct];
    }
    __syncthreads();

    if (kh == 0) {
        const float* src = Osc + qh * 2048;
#pragma unroll
        for (int mi = 0; mi < 2; ++mi)
#pragma unroll
            for (int ct = 0; ct < 4; ++ct)
                o[mi][ct] += *(const f32x4*)(src + (mi * 4 + ct) * 256 + lane * 4);
#pragma unroll
        for (int mi = 0; mi < 2; ++mi)
#pragma unroll
            for (int r = 0; r < 4; ++r) {
                const int qrow = mi * 16 + quad * 4 + r;
                const float l = Lred[(qh * 2) * 32 + qrow] + Lred[(qh * 2 + 1) * 32 + qrow];
                const float inv = 1.0f / l;
                bf16* orow = att + (size_t)(b * 2048 + q0 + qh * 32 + qrow) * 1024 + h * 64 + l16;
#pragma unroll
                for (int ct = 0; ct < 4; ++ct)
                    orow[ct * 16] = (bf16)(o[mi][ct][r] * inv);
            }
    }
}

// ---------------- launch ----------------

extern "C" void kernel_launch(void* const* d_in, const int* in_sizes, int n_in,
                              void* d_out, int out_size, void* d_ws, size_t ws_size,
                              hipStream_t stream) {
    (void)in_sizes; (void)n_in; (void)out_size; (void)ws_size;
    const float* x  = (const float*)d_in[0];
    const float* Wq = (const float*)d_in[1];
    const float* Wk = (const float*)d_in[2];
    const float* Wv = (const float*)d_in[3];
    const float* Wo = (const float*)d_in[4];

    char* ws = (char*)d_ws;
    bf16* xb    = (bf16*)(ws);                             // 8 MB  [4096][1024]
    bf16* att   = xb;                                      // alias: xb dead after QKV GEMM
    bf16* WqkvT = (bf16*)(ws + (size_t)8  * 1024 * 1024);  // 6 MB [3072][1024]
    bf16* WoT   = (bf16*)(ws + (size_t)14 * 1024 * 1024);  // 2 MB [1024][1024]
    bf16* QKV   = (bf16*)(ws + (size_t)16 * 1024 * 1024);  // 24 MB [4096][3072] (V region unused)
    bf16* VT    = (bf16*)(ws + (size_t)40 * 1024 * 1024);  // 8 MB [1024][4096]
    // total 48 MB

    // x->bf16 (z=4) + all 4 weight transposes (z=0..3); Wq pre-scaled
    prep<<<dim3(32, 32, 5), 256, 0, stream>>>(x, Wq, Wk, Wv, Wo, xb, WqkvT, WoT);

    // QKV = xb @ [Wq|Wk|Wv] : M=4096 N=3072 K=1024 (768 blocks = 3/CU);
    // V-tiles stored transposed straight to VT (transpose_v fused away)
    gemm_bt<false><<<dim3(3072 / 128, 4096 / 128), 256, 0, stream>>>(
        xb, WqkvT, QKV, 4096, 3072, 1024, VT);

    // attention -> att[bs][hc]; grid (bh, qt): 512 blocks = 2/CU (8 waves ea)
    flash_attn<<<dim3(32, 16), 512, 0, stream>>>(QKV, VT, att);

    // out = att @ Wo : M=4096 N=1024 K=1024, fp32 out, 64x128 tile (2 blk/CU)
    gemm_tm2<<<dim3(1024 / 128, 4096 / 64), 256, 0, stream>>>(
        att, WoT, (float*)d_out, 4096, 1024, 1024);
}

// Round 4
// 193.133 us; speedup vs baseline: 1.3638x; 1.3638x over previous
//
#include <hip/hip_runtime.h>
#include <hip/hip_bf16.h>
#include <stdint.h>
#include <stddef.h>

// B=2, S=2048, D=1024, H=16, C=64
typedef __bf16 bf16;
typedef __bf16 bf16x4 __attribute__((ext_vector_type(4)));
typedef __bf16 bf16x8 __attribute__((ext_vector_type(8)));
typedef float f32x4 __attribute__((ext_vector_type(4)));

#define DEV __device__ __forceinline__

// async global->LDS, 16B per lane; LDS dest is wave-uniform base + lane*16
DEV void async16(const bf16* g, bf16* l) {
    __builtin_amdgcn_global_load_lds(
        (const __attribute__((address_space(1))) void*)g,
        (__attribute__((address_space(3))) void*)l,
        16, 0, 0);
}

// pack two f32 -> two bf16 (truncation) in ONE v_perm_b32.
// Truncation bias cancels in P/l since l is computed from the same packed P.
DEV uint32_t pktrunc(float lo, float hi) {
    return __builtin_amdgcn_perm(__builtin_bit_cast(uint32_t, hi),
                                 __builtin_bit_cast(uint32_t, lo), 0x07060302u);
}

// ---------------- prep: x->bf16 convert (z=4) + 4 weight transposes (z=0..3) --

__global__ void prep(const float* __restrict__ x,
                     const float* __restrict__ Wq, const float* __restrict__ Wk,
                     const float* __restrict__ Wv, const float* __restrict__ Wo,
                     bf16* __restrict__ xb, bf16* __restrict__ WqkvT,
                     bf16* __restrict__ WoT) {
    __shared__ float t[32][33];
    if (blockIdx.z == 4) {
        const int bid = blockIdx.y * 32 + blockIdx.x;
#pragma unroll
        for (int i = 0; i < 4; ++i) {
            const int idx = ((bid * 4 + i) * 256 + threadIdx.x) * 4;
            const float4 v = *(const float4*)(x + idx);
            bf16 o4[4] = {(bf16)v.x, (bf16)v.y, (bf16)v.z, (bf16)v.w};
            *(uint2*)(xb + idx) = *(const uint2*)o4;
        }
        return;
    }
    const float* src;
    bf16* dst;
    float scale = 1.0f;
    switch (blockIdx.z) {
        case 0: src = Wq; dst = WqkvT; scale = 0.125f * 1.4426950408889634f; break;
        case 1: src = Wk; dst = WqkvT + 1024 * 1024; break;
        case 2: src = Wv; dst = WqkvT + 2 * 1024 * 1024; break;
        default: src = Wo; dst = WoT; break;
    }
    const int c0 = blockIdx.x * 32, r0 = blockIdx.y * 32;
    const int tx = threadIdx.x & 31, ty = threadIdx.x >> 5;  // 32x8
#pragma unroll
    for (int i = 0; i < 32; i += 8)
        t[ty + i][tx] = src[(size_t)(r0 + ty + i) * 1024 + c0 + tx];
    __syncthreads();
#pragma unroll
    for (int i = 0; i < 32; i += 8)
        dst[(size_t)(c0 + ty + i) * 1024 + r0 + tx] = (bf16)(t[tx][ty + i] * scale);
}

// ---------------- GEMM (TM=4): C[m][n] = sum_k A[m][k] * BT[n][k] ----------
// 128x128 tile, BK=64 as two BK=32 panels. If VTout != nullptr, tiles with
// n0 >= 2048 are stored TRANSPOSED to VTout[n-2048][m] (bf16) instead of C.

template <bool OUT_F32>
__global__ __launch_bounds__(256, 3) void gemm_bt(
    const bf16* __restrict__ A, const bf16* __restrict__ BT, void* __restrict__ Cout,
    int M, int N, int K, bf16* __restrict__ VTout) {
    __shared__ __attribute__((aligned(16))) bf16 As[2 * 128 * 32];
    __shared__ __attribute__((aligned(16))) bf16 Bs[2 * 128 * 32];
    const int tid = threadIdx.x;
    const int wid = tid >> 6;
    const int lane = tid & 63;
    const int quad = lane >> 4;
    const int l16 = lane & 15;
    const int wm = wid >> 1, wn = wid & 1;
    const int m0 = blockIdx.y * 128, n0 = blockIdx.x * 128;

    const int srow = wid * 32 + (lane >> 2);
    const int skcol = (lane & 3) * 8;
    const bf16* ag = A + (size_t)(m0 + srow) * K + skcol;
    const bf16* bg = BT + (size_t)(n0 + srow) * K + skcol;

    f32x4 acc[4][4];
#pragma unroll
    for (int i = 0; i < 4; ++i)
#pragma unroll
        for (int j = 0; j < 4; ++j) acc[i][j] = (f32x4){0.f, 0.f, 0.f, 0.f};

    for (int k0 = 0; k0 < K; k0 += 64) {
#pragma unroll
        for (int p = 0; p < 2; ++p) {
            async16(ag + k0 + p * 32, &As[p * 4096 + (wid * 32) * 32]);
            async16(ag + (size_t)16 * K + k0 + p * 32, &As[p * 4096 + (wid * 32 + 16) * 32]);
            async16(bg + k0 + p * 32, &Bs[p * 4096 + (wid * 32) * 32]);
            async16(bg + (size_t)16 * K + k0 + p * 32, &Bs[p * 4096 + (wid * 32 + 16) * 32]);
        }
        __syncthreads();

#pragma unroll
        for (int ks = 0; ks < 2; ++ks) {
            bf16x8 af[4], bfr[4];
#pragma unroll
            for (int mi = 0; mi < 4; ++mi)
                af[mi] = *(const bf16x8*)&As[ks * 4096 + (wm * 64 + mi * 16 + l16) * 32 + quad * 8];
#pragma unroll
            for (int ni = 0; ni < 4; ++ni)
                bfr[ni] = *(const bf16x8*)&Bs[ks * 4096 + (wn * 64 + ni * 16 + l16) * 32 + quad * 8];
#pragma unroll
            for (int mi = 0; mi < 4; ++mi)
#pragma unroll
                for (int ni = 0; ni < 4; ++ni)
                    acc[mi][ni] = __builtin_amdgcn_mfma_f32_16x16x32_bf16(
                        af[mi], bfr[ni], acc[mi][ni], 0, 0, 0);
        }
        __syncthreads();
    }

    if (VTout && n0 >= 2048) {
        // store transposed: VT[n-2048][m], pack 4 consecutive m (r) as 8B
#pragma unroll
        for (int mi = 0; mi < 4; ++mi)
#pragma unroll
            for (int ni = 0; ni < 4; ++ni) {
                bf16 pk[4] = {(bf16)acc[mi][ni][0], (bf16)acc[mi][ni][1],
                              (bf16)acc[mi][ni][2], (bf16)acc[mi][ni][3]};
                *(uint2*)&VTout[(size_t)(n0 - 2048 + wn * 64 + ni * 16 + l16) * 4096 +
                                (m0 + wm * 64 + mi * 16 + quad * 4)] = *(const uint2*)pk;
            }
        return;
    }
    if (OUT_F32) {
        float* C = (float*)Cout;
#pragma unroll
        for (int mi = 0; mi < 4; ++mi)
#pragma unroll
            for (int ni = 0; ni < 4; ++ni)
#pragma unroll
                for (int r = 0; r < 4; ++r)
                    C[(size_t)(m0 + wm * 64 + mi * 16 + quad * 4 + r) * N +
                      (n0 + wn * 64 + ni * 16 + l16)] = acc[mi][ni][r];
    } else {
        bf16* C = (bf16*)Cout;
#pragma unroll
        for (int mi = 0; mi < 4; ++mi)
#pragma unroll
            for (int ni = 0; ni < 4; ++ni)
#pragma unroll
                for (int r = 0; r < 4; ++r)
                    C[(size_t)(m0 + wm * 64 + mi * 16 + quad * 4 + r) * N +
                      (n0 + wn * 64 + ni * 16 + l16)] = (bf16)acc[mi][ni][r];
    }
}

// ---------------- GEMM (TM=2): 64x128 tile, fp32 out --------------------

__global__ __launch_bounds__(256, 4) void gemm_tm2(
    const bf16* __restrict__ A, const bf16* __restrict__ BT, float* __restrict__ C,
    int M, int N, int K) {
    __shared__ __attribute__((aligned(16))) bf16 As[2 * 64 * 32];
    __shared__ __attribute__((aligned(16))) bf16 Bs[2 * 128 * 32];
    const int tid = threadIdx.x;
    const int wid = tid >> 6;
    const int lane = tid & 63;
    const int quad = lane >> 4;
    const int l16 = lane & 15;
    const int wm = wid >> 1, wn = wid & 1;
    const int m0 = blockIdx.y * 64, n0 = blockIdx.x * 128;

    const int srowA = wid * 16 + (lane >> 2);
    const int srowB = wid * 32 + (lane >> 2);
    const int skcol = (lane & 3) * 8;
    const bf16* ag = A + (size_t)(m0 + srowA) * K + skcol;
    const bf16* bg = BT + (size_t)(n0 + srowB) * K + skcol;

    f32x4 acc[2][4];
#pragma unroll
    for (int i = 0; i < 2; ++i)
#pragma unroll
        for (int j = 0; j < 4; ++j) acc[i][j] = (f32x4){0.f, 0.f, 0.f, 0.f};

    for (int k0 = 0; k0 < K; k0 += 64) {
#pragma unroll
        for (int p = 0; p < 2; ++p) {
            async16(ag + k0 + p * 32, &As[p * 2048 + (wid * 16) * 32]);
            async16(bg + k0 + p * 32, &Bs[p * 4096 + (wid * 32) * 32]);
            async16(bg + (size_t)16 * K + k0 + p * 32, &Bs[p * 4096 + (wid * 32 + 16) * 32]);
        }
        __syncthreads();

#pragma unroll
        for (int ks = 0; ks < 2; ++ks) {
            bf16x8 af[2], bfr[4];
#pragma unroll
            for (int mi = 0; mi < 2; ++mi)
                af[mi] = *(const bf16x8*)&As[ks * 2048 + (wm * 32 + mi * 16 + l16) * 32 + quad * 8];
#pragma unroll
            for (int ni = 0; ni < 4; ++ni)
                bfr[ni] = *(const bf16x8*)&Bs[ks * 4096 + (wn * 64 + ni * 16 + l16) * 32 + quad * 8];
#pragma unroll
            for (int mi = 0; mi < 2; ++mi)
#pragma unroll
                for (int ni = 0; ni < 4; ++ni)
                    acc[mi][ni] = __builtin_amdgcn_mfma_f32_16x16x32_bf16(
                        af[mi], bfr[ni], acc[mi][ni], 0, 0, 0);
        }
        __syncthreads();
    }

#pragma unroll
    for (int mi = 0; mi < 2; ++mi)
#pragma unroll
        for (int ni = 0; ni < 4; ++ni)
#pragma unroll
            for (int r = 0; r < 4; ++r)
                C[(size_t)(m0 + wm * 32 + mi * 16 + quad * 4 + r) * N +
                  (n0 + wn * 64 + ni * 16 + l16)] = acc[mi][ni][r];
}

// ---------------- flash attention (v15 = v13 + K/V double-buffer) ----------
// v14 post-mortem: V-from-L2 scattered 8B loads = 16 L2 txns/inst -> 135us.
// V must stay in LDS. v13 post-mortem: wall invariant to occupancy AND LDS
// bytes -> 2-barrier lockstep is the limiter (stage/compute never overlap).
// v15: v13's exact geometry + math (Q=128/block, 128-key iters, LDK=72,
// LDV=136, 512 thr) but BOTH K and V double-buffered (2 x 35840 B = 71.7 KB,
// 2 blk/CU) -> ONE barrier per iter; waves skew, staging overlaps compute.
// T5 setprio(1) around the MFMA cluster (phase diversity now exists).

__global__ __launch_bounds__(512, 4) void flash_attn(
    const bf16* __restrict__ QKV, const bf16* __restrict__ VT, bf16* __restrict__ att) {
    constexpr int LDK = 72;   // Ks stride: frag-read banks conflict-clean
    constexpr int LDV = 136;  // Vs stride: b64 reads 2-way (free), writes 8-phase
    constexpr int BUFB = 128 * LDK * 2 + 64 * LDV * 2;  // 18432 + 17408 = 35840 B
    __shared__ __attribute__((aligned(16))) char smem[2 * BUFB + 1024];
    float* Osc = (float*)smem;                 // epilogue alias: 4 x 8 KB (buf0)
    float* Lred = (float*)(smem + 2 * BUFB);   // [8][32] floats

    const int tid = threadIdx.x, wid = tid >> 6, lane = tid & 63;
    const int quad = lane >> 4, l16 = lane & 15;
    const int qh = wid >> 1, kh = wid & 1;        // qh 0..3 (32 q-rows), kh 0..1
    const int bh = blockIdx.x, qt = blockIdx.y;   // XCD = bh % 8 (L2-local K/V)
    const int b = bh >> 4, h = bh & 15;
    const int q0 = qt * 128;

    // ---- Q B-frags (resident): B[k=quad*8+j][n=l16] = Q[q][c] ----
    bf16x8 qf[2][2];
    {
        const bf16* qbase = QKV + (size_t)(b * 2048 + q0 + qh * 32 + l16) * 3072 + h * 64 + quad * 8;
#pragma unroll
        for (int mi = 0; mi < 2; ++mi)
#pragma unroll
            for (int ks = 0; ks < 2; ++ks)
                qf[mi][ks] = *(const bf16x8*)(qbase + (size_t)mi * 16 * 3072 + ks * 32);
    }

    // staging geometry (coalesced, 512 threads): K 128 rows x 128 B as 2
    // passes of 64 rows (8 lanes/row); V 64 rows x 256 B as 2 passes of 32
    const int krow = tid >> 3, kcol = (tid & 7) * 8;   // krow 0..63
    const int vrow = tid >> 4, vcol = (tid & 15) * 8;  // vrow 0..31
    const bf16* kg = QKV + (size_t)(b * 2048 + krow) * 3072 + 1024 + h * 64 + kcol;
    const bf16* vg = VT + (size_t)(h * 64 + vrow) * 4096 + b * 2048 + vcol;

    bf16x8 kr[2], vr[2];
#pragma unroll
    for (int p = 0; p < 2; ++p) {
        kr[p] = *(const bf16x8*)(kg + (size_t)(64 * p) * 3072);
        vr[p] = *(const bf16x8*)(vg + (size_t)(32 * p) * 4096);
    }

    const bf16 one = (bf16)1.0f;
    const bf16x8 onesf = (bf16x8){one, one, one, one, one, one, one, one};

    f32x4 o[2][4];
    f32x4 ls[2];
#pragma unroll
    for (int mi = 0; mi < 2; ++mi) {
        ls[mi] = (f32x4){0.f, 0.f, 0.f, 0.f};
#pragma unroll
        for (int ct = 0; ct < 4; ++ct) o[mi][ct] = (f32x4){0.f, 0.f, 0.f, 0.f};
    }

    for (int it = 0; it < 16; ++it) {
        bf16* Ks = (bf16*)(smem + (it & 1) * BUFB);
        bf16* Vs = (bf16*)(smem + (it & 1) * BUFB + 128 * LDK * 2);

        // ---- stage prefetched regs -> LDS (dbuf: ONE barrier per iter) ----
#pragma unroll
        for (int p = 0; p < 2; ++p) {
            *(bf16x8*)&Ks[(64 * p + krow) * LDK + kcol] = kr[p];
            *(bf16x8*)&Vs[(32 * p + vrow) * LDV + vcol] = vr[p];
        }
        __syncthreads();

        // ---- prefetch next big-iter (hidden behind compute phase) ----
        if (it < 15) {
            const size_t ko = (size_t)(it + 1) * 128;
#pragma unroll
            for (int p = 0; p < 2; ++p) {
                kr[p] = *(const bf16x8*)(kg + (ko + 64 * p) * 3072);
                vr[p] = *(const bf16x8*)(vg + (size_t)(32 * p) * 4096 + ko);
            }
        }

        // ---- compute: wave's 64 keys as 2 pairs of 16-key groups ----
#pragma unroll
        for (int pr = 0; pr < 2; ++pr) {
            const int kb = kh * 64 + pr * 32;  // pair base (rel key)
            const bf16x8 kfA0 = *(const bf16x8*)&Ks[(kb + l16) * LDK + quad * 8];
            const bf16x8 kfA1 = *(const bf16x8*)&Ks[(kb + l16) * LDK + 32 + quad * 8];
            const bf16x8 kfB0 = *(const bf16x8*)&Ks[(kb + 16 + l16) * LDK + quad * 8];
            const bf16x8 kfB1 = *(const bf16x8*)&Ks[(kb + 16 + l16) * LDK + 32 + quad * 8];
            bf16x8 vf[4];
#pragma unroll
            for (int ct = 0; ct < 4; ++ct) {
                const bf16x4 lo = *(const bf16x4*)&Vs[(ct * 16 + l16) * LDV + kb + quad * 4];
                const bf16x4 hi = *(const bf16x4*)&Vs[(ct * 16 + l16) * LDV + kb + 16 + quad * 4];
                vf[ct] = (bf16x8){lo[0], lo[1], lo[2], lo[3], hi[0], hi[1], hi[2], hi[3]};
            }
            __builtin_amdgcn_s_setprio(1);
#pragma unroll
            for (int mi = 0; mi < 2; ++mi) {
                f32x4 sA = (f32x4){0.f, 0.f, 0.f, 0.f};
                f32x4 sB = (f32x4){0.f, 0.f, 0.f, 0.f};
                sA = __builtin_amdgcn_mfma_f32_16x16x32_bf16(kfA0, qf[mi][0], sA, 0, 0, 0);
                sA = __builtin_amdgcn_mfma_f32_16x16x32_bf16(kfA1, qf[mi][1], sA, 0, 0, 0);
                sB = __builtin_amdgcn_mfma_f32_16x16x32_bf16(kfB0, qf[mi][0], sB, 0, 0, 0);
                sB = __builtin_amdgcn_mfma_f32_16x16x32_bf16(kfB1, qf[mi][1], sB, 0, 0, 0);

                const float pa0 = __builtin_amdgcn_exp2f(sA[0]);
                const float pa1 = __builtin_amdgcn_exp2f(sA[1]);
                const float pa2 = __builtin_amdgcn_exp2f(sA[2]);
                const float pa3 = __builtin_amdgcn_exp2f(sA[3]);
                const float pb0 = __builtin_amdgcn_exp2f(sB[0]);
                const float pb1 = __builtin_amdgcn_exp2f(sB[1]);
                const float pb2 = __builtin_amdgcn_exp2f(sB[2]);
                const float pb3 = __builtin_amdgcn_exp2f(sB[3]);

                // P A-frag via truncation pack (4 v_perm); lane = P[q=l16][j0..7]
                union { uint32_t u[4]; bf16x8 v; } pu;
                pu.u[0] = pktrunc(pa0, pa1);
                pu.u[1] = pktrunc(pa2, pa3);
                pu.u[2] = pktrunc(pb0, pb1);
                pu.u[3] = pktrunc(pb2, pb3);
                const bf16x8 pf = pu.v;
#pragma unroll
                for (int ct = 0; ct < 4; ++ct)
                    o[mi][ct] = __builtin_amdgcn_mfma_f32_16x16x32_bf16(pf, vf[ct], o[mi][ct], 0, 0, 0);
                // l-sum on the matrix pipe: D[q][*] = sum_k pf (all cols equal)
                ls[mi] = __builtin_amdgcn_mfma_f32_16x16x32_bf16(pf, onesf, ls[mi], 0, 0, 0);
            }
            __builtin_amdgcn_s_setprio(0);
        }
        // no trailing barrier: next iter's stage targets the other buffer
    }
    __syncthreads();  // Osc aliases buf0: wait for all compute before epilogue

    // ---- epilogue: publish l (q = mi*16+quad*4+r), cross-wave O reduce ----
    if (l16 == 0) {
#pragma unroll
        for (int mi = 0; mi < 2; ++mi)
#pragma unroll
            for (int r = 0; r < 4; ++r)
                Lred[wid * 32 + mi * 16 + quad * 4 + r] = ls[mi][r];
    }
    if (kh == 1) {
        float* dst = Osc + qh * 2048;
#pragma unroll
        for (int mi = 0; mi < 2; ++mi)
#pragma unroll
            for (int ct = 0; ct < 4; ++ct)
                *(f32x4*)(dst + (mi * 4 + ct) * 256 + lane * 4) = o[mi][ct];
    }
    __syncthreads();

    if (kh == 0) {
        const float* src = Osc + qh * 2048;
#pragma unroll
        for (int mi = 0; mi < 2; ++mi)
#pragma unroll
            for (int ct = 0; ct < 4; ++ct)
                o[mi][ct] += *(const f32x4*)(src + (mi * 4 + ct) * 256 + lane * 4);
#pragma unroll
        for (int mi = 0; mi < 2; ++mi)
#pragma unroll
            for (int r = 0; r < 4; ++r) {
                const int qrow = mi * 16 + quad * 4 + r;
                const float l = Lred[(qh * 2) * 32 + qrow] + Lred[(qh * 2 + 1) * 32 + qrow];
                const float inv = 1.0f / l;
                bf16* orow = att + (size_t)(b * 2048 + q0 + qh * 32 + qrow) * 1024 + h * 64 + l16;
#pragma unroll
                for (int ct = 0; ct < 4; ++ct)
                    orow[ct * 16] = (bf16)(o[mi][ct][r] * inv);
            }
    }
}

// ---------------- launch ----------------

extern "C" void kernel_launch(void* const* d_in, const int* in_sizes, int n_in,
                              void* d_out, int out_size, void* d_ws, size_t ws_size,
                              hipStream_t stream) {
    (void)in_sizes; (void)n_in; (void)out_size; (void)ws_size;
    const float* x  = (const float*)d_in[0];
    const float* Wq = (const float*)d_in[1];
    const float* Wk = (const float*)d_in[2];
    const float* Wv = (const float*)d_in[3];
    const float* Wo = (const float*)d_in[4];

    char* ws = (char*)d_ws;
    bf16* xb    = (bf16*)(ws);                             // 8 MB  [4096][1024]
    bf16* att   = xb;                                      // alias: xb dead after QKV GEMM
    bf16* WqkvT = (bf16*)(ws + (size_t)8  * 1024 * 1024);  // 6 MB [3072][1024]
    bf16* WoT   = (bf16*)(ws + (size_t)14 * 1024 * 1024);  // 2 MB [1024][1024]
    bf16* QKV   = (bf16*)(ws + (size_t)16 * 1024 * 1024);  // 24 MB [4096][3072] (V region unused)
    bf16* VT    = (bf16*)(ws + (size_t)40 * 1024 * 1024);  // 8 MB [1024][4096]
    // total 48 MB

    // x->bf16 (z=4) + all 4 weight transposes (z=0..3); Wq pre-scaled
    prep<<<dim3(32, 32, 5), 256, 0, stream>>>(x, Wq, Wk, Wv, Wo, xb, WqkvT, WoT);

    // QKV = xb @ [Wq|Wk|Wv] : M=4096 N=3072 K=1024 (768 blocks = 3/CU);
    // V-tiles stored transposed straight to VT (transpose_v fused away)
    gemm_bt<false><<<dim3(3072 / 128, 4096 / 128), 256, 0, stream>>>(
        xb, WqkvT, QKV, 4096, 3072, 1024, VT);

    // attention -> att[bs][hc]; grid (bh, qt): 512 blocks = 2/CU (8 waves ea)
    flash_attn<<<dim3(32, 16), 512, 0, stream>>>(QKV, VT, att);

    // out = att @ Wo : M=4096 N=1024 K=1024, fp32 out, 64x128 tile (2 blk/CU)
    gemm_tm2<<<dim3(1024 / 128, 4096 / 64), 256, 0, stream>>>(
        att, WoT, (float*)d_out, 4096, 1024, 1024);
}

// Round 5
// 174.606 us; speedup vs baseline: 1.5086x; 1.1061x over previous
//
#include <hip/hip_runtime.h>
#include <hip/hip_bf16.h>
#include <stdint.h>
#include <stddef.h>

// B=2, S=2048, D=1024, H=16, C=64
typedef __bf16 bf16;
typedef __bf16 bf16x4 __attribute__((ext_vector_type(4)));
typedef __bf16 bf16x8 __attribute__((ext_vector_type(8)));
typedef float f32x4 __attribute__((ext_vector_type(4)));

#define DEV __device__ __forceinline__

// async global->LDS, 16B per lane; LDS dest is wave-uniform base + lane*16
DEV void async16(const bf16* g, bf16* l) {
    __builtin_amdgcn_global_load_lds(
        (const __attribute__((address_space(1))) void*)g,
        (__attribute__((address_space(3))) void*)l,
        16, 0, 0);
}

// pack two f32 -> two bf16 (truncation) in ONE v_perm_b32.
// Truncation bias cancels in P/l since l is computed from the same packed P.
DEV uint32_t pktrunc(float lo, float hi) {
    return __builtin_amdgcn_perm(__builtin_bit_cast(uint32_t, hi),
                                 __builtin_bit_cast(uint32_t, lo), 0x07060302u);
}

// ---------------- prep: x->bf16 convert (z=4) + 4 weight transposes (z=0..3) --

__global__ void prep(const float* __restrict__ x,
                     const float* __restrict__ Wq, const float* __restrict__ Wk,
                     const float* __restrict__ Wv, const float* __restrict__ Wo,
                     bf16* __restrict__ xb, bf16* __restrict__ WqkvT,
                     bf16* __restrict__ WoT) {
    __shared__ float t[32][33];
    if (blockIdx.z == 4) {
        const int bid = blockIdx.y * 32 + blockIdx.x;
#pragma unroll
        for (int i = 0; i < 4; ++i) {
            const int idx = ((bid * 4 + i) * 256 + threadIdx.x) * 4;
            const float4 v = *(const float4*)(x + idx);
            bf16 o4[4] = {(bf16)v.x, (bf16)v.y, (bf16)v.z, (bf16)v.w};
            *(uint2*)(xb + idx) = *(const uint2*)o4;
        }
        return;
    }
    const float* src;
    bf16* dst;
    float scale = 1.0f;
    switch (blockIdx.z) {
        case 0: src = Wq; dst = WqkvT; scale = 0.125f * 1.4426950408889634f; break;
        case 1: src = Wk; dst = WqkvT + 1024 * 1024; break;
        case 2: src = Wv; dst = WqkvT + 2 * 1024 * 1024; break;
        default: src = Wo; dst = WoT; break;
    }
    const int c0 = blockIdx.x * 32, r0 = blockIdx.y * 32;
    const int tx = threadIdx.x & 31, ty = threadIdx.x >> 5;  // 32x8
#pragma unroll
    for (int i = 0; i < 32; i += 8)
        t[ty + i][tx] = src[(size_t)(r0 + ty + i) * 1024 + c0 + tx];
    __syncthreads();
#pragma unroll
    for (int i = 0; i < 32; i += 8)
        dst[(size_t)(c0 + ty + i) * 1024 + r0 + tx] = (bf16)(t[tx][ty + i] * scale);
}

// ---------------- GEMM (TM=4): C[m][n] = sum_k A[m][k] * BT[n][k] ----------
// 128x128 tile, BK=64 as two BK=32 panels. If VTout != nullptr, tiles with
// n0 >= 2048 are stored TRANSPOSED to VTout[n-2048][m] (bf16) instead of C.
// bf16 C path: epilogue staged through LDS (As/Bs dead after k-loop) ->
// 256B-contiguous dwordx4 stores instead of 64 scalar 2B stores/thread.

template <bool OUT_F32>
__global__ __launch_bounds__(256, 3) void gemm_bt(
    const bf16* __restrict__ A, const bf16* __restrict__ BT, void* __restrict__ Cout,
    int M, int N, int K, bf16* __restrict__ VTout) {
    __shared__ __attribute__((aligned(16))) bf16 smem[2 * 128 * 32 * 2];  // As|Bs, 32 KB
    bf16* As = smem;
    bf16* Bs = smem + 2 * 128 * 32;
    const int tid = threadIdx.x;
    const int wid = tid >> 6;
    const int lane = tid & 63;
    const int quad = lane >> 4;
    const int l16 = lane & 15;
    const int wm = wid >> 1, wn = wid & 1;
    const int m0 = blockIdx.y * 128, n0 = blockIdx.x * 128;

    const int srow = wid * 32 + (lane >> 2);
    const int skcol = (lane & 3) * 8;
    const bf16* ag = A + (size_t)(m0 + srow) * K + skcol;
    const bf16* bg = BT + (size_t)(n0 + srow) * K + skcol;

    f32x4 acc[4][4];
#pragma unroll
    for (int i = 0; i < 4; ++i)
#pragma unroll
        for (int j = 0; j < 4; ++j) acc[i][j] = (f32x4){0.f, 0.f, 0.f, 0.f};

    for (int k0 = 0; k0 < K; k0 += 64) {
#pragma unroll
        for (int p = 0; p < 2; ++p) {
            async16(ag + k0 + p * 32, &As[p * 4096 + (wid * 32) * 32]);
            async16(ag + (size_t)16 * K + k0 + p * 32, &As[p * 4096 + (wid * 32 + 16) * 32]);
            async16(bg + k0 + p * 32, &Bs[p * 4096 + (wid * 32) * 32]);
            async16(bg + (size_t)16 * K + k0 + p * 32, &Bs[p * 4096 + (wid * 32 + 16) * 32]);
        }
        __syncthreads();

#pragma unroll
        for (int ks = 0; ks < 2; ++ks) {
            bf16x8 af[4], bfr[4];
#pragma unroll
            for (int mi = 0; mi < 4; ++mi)
                af[mi] = *(const bf16x8*)&As[ks * 4096 + (wm * 64 + mi * 16 + l16) * 32 + quad * 8];
#pragma unroll
            for (int ni = 0; ni < 4; ++ni)
                bfr[ni] = *(const bf16x8*)&Bs[ks * 4096 + (wn * 64 + ni * 16 + l16) * 32 + quad * 8];
#pragma unroll
            for (int mi = 0; mi < 4; ++mi)
#pragma unroll
                for (int ni = 0; ni < 4; ++ni)
                    acc[mi][ni] = __builtin_amdgcn_mfma_f32_16x16x32_bf16(
                        af[mi], bfr[ni], acc[mi][ni], 0, 0, 0);
        }
        __syncthreads();
    }

    if (VTout && n0 >= 2048) {
        // store transposed: VT[n-2048][m], pack 4 consecutive m (r) as 8B
#pragma unroll
        for (int mi = 0; mi < 4; ++mi)
#pragma unroll
            for (int ni = 0; ni < 4; ++ni) {
                bf16 pk[4] = {(bf16)acc[mi][ni][0], (bf16)acc[mi][ni][1],
                              (bf16)acc[mi][ni][2], (bf16)acc[mi][ni][3]};
                *(uint2*)&VTout[(size_t)(n0 - 2048 + wn * 64 + ni * 16 + l16) * 4096 +
                                (m0 + wm * 64 + mi * 16 + quad * 4)] = *(const uint2*)pk;
            }
        return;
    }
    if constexpr (OUT_F32) {
        float* C = (float*)Cout;
#pragma unroll
        for (int mi = 0; mi < 4; ++mi)
#pragma unroll
            for (int ni = 0; ni < 4; ++ni)
#pragma unroll
                for (int r = 0; r < 4; ++r)
                    C[(size_t)(m0 + wm * 64 + mi * 16 + quad * 4 + r) * N +
                      (n0 + wn * 64 + ni * 16 + l16)] = acc[mi][ni][r];
    } else {
        // stage tile in LDS (k-loop ended with a barrier; As/Bs are dead)
        bf16* Ct = smem;  // [128][128] bf16 = 32768 B, exact fit
#pragma unroll
        for (int mi = 0; mi < 4; ++mi)
#pragma unroll
            for (int ni = 0; ni < 4; ++ni)
#pragma unroll
                for (int r = 0; r < 4; ++r)
                    Ct[(wm * 64 + mi * 16 + quad * 4 + r) * 128 + wn * 64 + ni * 16 + l16] =
                        (bf16)acc[mi][ni][r];
        __syncthreads();
        bf16* C = (bf16*)Cout;
#pragma unroll
        for (int p = 0; p < 8; ++p) {
            const int r = p * 16 + (tid >> 4);   // 16 rows per pass
            const int c = (tid & 15) * 8;        // 16B per lane, 256B/row
            *(bf16x8*)(C + (size_t)(m0 + r) * N + n0 + c) = *(const bf16x8*)&Ct[r * 128 + c];
        }
    }
}

// ---------------- GEMM (TM=2): 64x128 tile, fp32 out --------------------

__global__ __launch_bounds__(256, 4) void gemm_tm2(
    const bf16* __restrict__ A, const bf16* __restrict__ BT, float* __restrict__ C,
    int M, int N, int K) {
    __shared__ __attribute__((aligned(16))) bf16 As[2 * 64 * 32];
    __shared__ __attribute__((aligned(16))) bf16 Bs[2 * 128 * 32];
    const int tid = threadIdx.x;
    const int wid = tid >> 6;
    const int lane = tid & 63;
    const int quad = lane >> 4;
    const int l16 = lane & 15;
    const int wm = wid >> 1, wn = wid & 1;
    const int m0 = blockIdx.y * 64, n0 = blockIdx.x * 128;

    const int srowA = wid * 16 + (lane >> 2);
    const int srowB = wid * 32 + (lane >> 2);
    const int skcol = (lane & 3) * 8;
    const bf16* ag = A + (size_t)(m0 + srowA) * K + skcol;
    const bf16* bg = BT + (size_t)(n0 + srowB) * K + skcol;

    f32x4 acc[2][4];
#pragma unroll
    for (int i = 0; i < 2; ++i)
#pragma unroll
        for (int j = 0; j < 4; ++j) acc[i][j] = (f32x4){0.f, 0.f, 0.f, 0.f};

    for (int k0 = 0; k0 < K; k0 += 64) {
#pragma unroll
        for (int p = 0; p < 2; ++p) {
            async16(ag + k0 + p * 32, &As[p * 2048 + (wid * 16) * 32]);
            async16(bg + k0 + p * 32, &Bs[p * 4096 + (wid * 32) * 32]);
            async16(bg + (size_t)16 * K + k0 + p * 32, &Bs[p * 4096 + (wid * 32 + 16) * 32]);
        }
        __syncthreads();

#pragma unroll
        for (int ks = 0; ks < 2; ++ks) {
            bf16x8 af[2], bfr[4];
#pragma unroll
            for (int mi = 0; mi < 2; ++mi)
                af[mi] = *(const bf16x8*)&As[ks * 2048 + (wm * 32 + mi * 16 + l16) * 32 + quad * 8];
#pragma unroll
            for (int ni = 0; ni < 4; ++ni)
                bfr[ni] = *(const bf16x8*)&Bs[ks * 4096 + (wn * 64 + ni * 16 + l16) * 32 + quad * 8];
#pragma unroll
            for (int mi = 0; mi < 2; ++mi)
#pragma unroll
                for (int ni = 0; ni < 4; ++ni)
                    acc[mi][ni] = __builtin_amdgcn_mfma_f32_16x16x32_bf16(
                        af[mi], bfr[ni], acc[mi][ni], 0, 0, 0);
        }
        __syncthreads();
    }

#pragma unroll
    for (int mi = 0; mi < 2; ++mi)
#pragma unroll
        for (int ni = 0; ni < 4; ++ni)
#pragma unroll
            for (int r = 0; r < 4; ++r)
                C[(size_t)(m0 + wm * 32 + mi * 16 + quad * 4 + r) * N +
                  (n0 + wn * 64 + ni * 16 + l16)] = acc[mi][ni][r];
}

// ---------------- flash attention (v16 = v11 EXACT + T5 setprio) ----------
// Structure ledger: v12 (Q=64 dbuf) 58.7, v13 (512thr lockstep) 48.7,
// v14 (V-from-L2) 135.6, v15 (K/V dbuf 1-barrier) 64.2 -- every deviation
// from v11's 2-barrier lockstep lost (v15: L2 skew, FETCH +8MB). Reverted
// to v11 (48.1 us proven). Only delta: setprio(1) around the MFMA/exp
// cluster -- 2 independent blocks/CU give the arbiter phase diversity (T5).

__global__ __launch_bounds__(256, 2) void flash_attn(
    const bf16* __restrict__ QKV, const bf16* __restrict__ VT, bf16* __restrict__ att) {
    constexpr int LDK = 72;   // Ks stride: frag-read banks 4*(l16+quad) uniform
    constexpr int LDV = 136;  // Vs stride: b64 reads 2-way (free), writes 8-phase
    __shared__ __attribute__((aligned(16))) char smem[36864];
    bf16* Ks = (bf16*)smem;                // [128][72]  = 18432 B
    bf16* Vs = (bf16*)(smem + 18432);      // [64][136]  = 17408 B -> 35840
    float* Osc = (float*)smem;             // epilogue alias: 2 regions x 16 KB
    float* Lred = (float*)(smem + 32768);  // [4][64] floats

    const int tid = threadIdx.x, wid = tid >> 6, lane = tid & 63;
    const int quad = lane >> 4, l16 = lane & 15;
    const int qh = wid >> 1, kh = wid & 1;
    const int bh = blockIdx.x, qt = blockIdx.y;   // XCD = bh % 8 (L2-local K/V)
    const int b = bh >> 4, h = bh & 15;
    const int q0 = qt * 128;

    // ---- Q B-frags (resident): B[k=quad*8+j][n=l16] = Q[q][c] ----
    bf16x8 qf[4][2];
    {
        const bf16* qbase = QKV + (size_t)(b * 2048 + q0 + qh * 64 + l16) * 3072 + h * 64 + quad * 8;
#pragma unroll
        for (int mi = 0; mi < 4; ++mi)
#pragma unroll
            for (int ks = 0; ks < 2; ++ks)
                qf[mi][ks] = *(const bf16x8*)(qbase + (size_t)mi * 16 * 3072 + ks * 32);
    }

    // staging geometry (coalesced): K 128 rows x 128 B, V 64 rows x 256 B
    const int krow = tid >> 3, kcol = (tid & 7) * 8;   // 32 rows/pass, 4 passes
    const int vrow = tid >> 4, vcol = (tid & 15) * 8;  // 16 rows/pass, 4 passes
    const bf16* kg = QKV + (size_t)(b * 2048 + krow) * 3072 + 1024 + h * 64 + kcol;
    const bf16* vg = VT + (size_t)(h * 64 + vrow) * 4096 + b * 2048 + vcol;

    bf16x8 kr[4], vr[4];
#pragma unroll
    for (int p = 0; p < 4; ++p) {
        kr[p] = *(const bf16x8*)(kg + (size_t)(32 * p) * 3072);
        vr[p] = *(const bf16x8*)(vg + (size_t)(16 * p) * 4096);
    }

    const bf16 one = (bf16)1.0f;
    const bf16x8 onesf = (bf16x8){one, one, one, one, one, one, one, one};

    f32x4 o[4][4];
    f32x4 ls[4];
#pragma unroll
    for (int mi = 0; mi < 4; ++mi) {
        ls[mi] = (f32x4){0.f, 0.f, 0.f, 0.f};
#pragma unroll
        for (int ct = 0; ct < 4; ++ct) o[mi][ct] = (f32x4){0.f, 0.f, 0.f, 0.f};
    }

    for (int it = 0; it < 16; ++it) {
        // ---- stage prefetched regs -> LDS ----
#pragma unroll
        for (int p = 0; p < 4; ++p) {
            *(bf16x8*)&Ks[(32 * p + krow) * LDK + kcol] = kr[p];
            *(bf16x8*)&Vs[(16 * p + vrow) * LDV + vcol] = vr[p];
        }
        __syncthreads();

        // ---- prefetch next big-iter (hidden behind compute phase) ----
        if (it < 15) {
            const size_t ko = (size_t)(it + 1) * 128;
#pragma unroll
            for (int p = 0; p < 4; ++p) {
                kr[p] = *(const bf16x8*)(kg + (ko + 32 * p) * 3072);
                vr[p] = *(const bf16x8*)(vg + (size_t)(16 * p) * 4096 + ko);
            }
        }

        // ---- compute: wave's 64 keys as 2 pairs of 16-key groups ----
#pragma unroll
        for (int pr = 0; pr < 2; ++pr) {
            const int kb = kh * 64 + pr * 32;  // pair base (rel key)
            const bf16x8 kfA0 = *(const bf16x8*)&Ks[(kb + l16) * LDK + quad * 8];
            const bf16x8 kfA1 = *(const bf16x8*)&Ks[(kb + l16) * LDK + 32 + quad * 8];
            const bf16x8 kfB0 = *(const bf16x8*)&Ks[(kb + 16 + l16) * LDK + quad * 8];
            const bf16x8 kfB1 = *(const bf16x8*)&Ks[(kb + 16 + l16) * LDK + 32 + quad * 8];
            bf16x8 vf[4];
#pragma unroll
            for (int ct = 0; ct < 4; ++ct) {
                const bf16x4 lo = *(const bf16x4*)&Vs[(ct * 16 + l16) * LDV + kb + quad * 4];
                const bf16x4 hi = *(const bf16x4*)&Vs[(ct * 16 + l16) * LDV + kb + 16 + quad * 4];
                vf[ct] = (bf16x8){lo[0], lo[1], lo[2], lo[3], hi[0], hi[1], hi[2], hi[3]};
            }
            __builtin_amdgcn_s_setprio(1);
#pragma unroll
            for (int mi = 0; mi < 4; ++mi) {
                f32x4 sA = (f32x4){0.f, 0.f, 0.f, 0.f};
                f32x4 sB = (f32x4){0.f, 0.f, 0.f, 0.f};
                sA = __builtin_amdgcn_mfma_f32_16x16x32_bf16(kfA0, qf[mi][0], sA, 0, 0, 0);
                sA = __builtin_amdgcn_mfma_f32_16x16x32_bf16(kfA1, qf[mi][1], sA, 0, 0, 0);
                sB = __builtin_amdgcn_mfma_f32_16x16x32_bf16(kfB0, qf[mi][0], sB, 0, 0, 0);
                sB = __builtin_amdgcn_mfma_f32_16x16x32_bf16(kfB1, qf[mi][1], sB, 0, 0, 0);

                const float pa0 = __builtin_amdgcn_exp2f(sA[0]);
                const float pa1 = __builtin_amdgcn_exp2f(sA[1]);
                const float pa2 = __builtin_amdgcn_exp2f(sA[2]);
                const float pa3 = __builtin_amdgcn_exp2f(sA[3]);
                const float pb0 = __builtin_amdgcn_exp2f(sB[0]);
                const float pb1 = __builtin_amdgcn_exp2f(sB[1]);
                const float pb2 = __builtin_amdgcn_exp2f(sB[2]);
                const float pb3 = __builtin_amdgcn_exp2f(sB[3]);

                // P A-frag via truncation pack (4 v_perm); lane = P[q=l16][j0..7]
                union { uint32_t u[4]; bf16x8 v; } pu;
                pu.u[0] = pktrunc(pa0, pa1);
                pu.u[1] = pktrunc(pa2, pa3);
                pu.u[2] = pktrunc(pb0, pb1);
                pu.u[3] = pktrunc(pb2, pb3);
                const bf16x8 pf = pu.v;
#pragma unroll
                for (int ct = 0; ct < 4; ++ct)
                    o[mi][ct] = __builtin_amdgcn_mfma_f32_16x16x32_bf16(pf, vf[ct], o[mi][ct], 0, 0, 0);
                // l-sum on the matrix pipe: D[q][*] = sum_k pf (all cols equal)
                ls[mi] = __builtin_amdgcn_mfma_f32_16x16x32_bf16(pf, onesf, ls[mi], 0, 0, 0);
            }
            __builtin_amdgcn_s_setprio(0);
        }
        __syncthreads();
    }

    // ---- epilogue: publish l (already row-summed, q = mi*16+quad*4+r), ----
    // ---- cross-wave O reduce ----
    if (l16 == 0) {
#pragma unroll
        for (int mi = 0; mi < 4; ++mi)
#pragma unroll
            for (int r = 0; r < 4; ++r)
                Lred[wid * 64 + mi * 16 + quad * 4 + r] = ls[mi][r];
    }
    if (kh == 1) {
        float* dst = Osc + qh * 4096;
#pragma unroll
        for (int mi = 0; mi < 4; ++mi)
#pragma unroll
            for (int ct = 0; ct < 4; ++ct)
                *(f32x4*)(dst + (mi * 4 + ct) * 256 + lane * 4) = o[mi][ct];
    }
    __syncthreads();

    if (kh == 0) {
        const float* src = Osc + qh * 4096;
#pragma unroll
        for (int mi = 0; mi < 4; ++mi)
#pragma unroll
            for (int ct = 0; ct < 4; ++ct)
                o[mi][ct] += *(const f32x4*)(src + (mi * 4 + ct) * 256 + lane * 4);
#pragma unroll
        for (int mi = 0; mi < 4; ++mi)
#pragma unroll
            for (int r = 0; r < 4; ++r) {
                const int qrow = mi * 16 + quad * 4 + r;
                const float l = Lred[(qh * 2) * 64 + qrow] + Lred[(qh * 2 + 1) * 64 + qrow];
                const float inv = 1.0f / l;
                bf16* orow = att + (size_t)(b * 2048 + q0 + qh * 64 + qrow) * 1024 + h * 64 + l16;
#pragma unroll
                for (int ct = 0; ct < 4; ++ct)
                    orow[ct * 16] = (bf16)(o[mi][ct][r] * inv);
            }
    }
}

// ---------------- launch ----------------

extern "C" void kernel_launch(void* const* d_in, const int* in_sizes, int n_in,
                              void* d_out, int out_size, void* d_ws, size_t ws_size,
                              hipStream_t stream) {
    (void)in_sizes; (void)n_in; (void)out_size; (void)ws_size;
    const float* x  = (const float*)d_in[0];
    const float* Wq = (const float*)d_in[1];
    const float* Wk = (const float*)d_in[2];
    const float* Wv = (const float*)d_in[3];
    const float* Wo = (const float*)d_in[4];

    char* ws = (char*)d_ws;
    bf16* xb    = (bf16*)(ws);                             // 8 MB  [4096][1024]
    bf16* att   = xb;                                      // alias: xb dead after QKV GEMM
    bf16* WqkvT = (bf16*)(ws + (size_t)8  * 1024 * 1024);  // 6 MB [3072][1024]
    bf16* WoT   = (bf16*)(ws + (size_t)14 * 1024 * 1024);  // 2 MB [1024][1024]
    bf16* QKV   = (bf16*)(ws + (size_t)16 * 1024 * 1024);  // 24 MB [4096][3072] (V region unused)
    bf16* VT    = (bf16*)(ws + (size_t)40 * 1024 * 1024);  // 8 MB [1024][4096]
    // total 48 MB

    // x->bf16 (z=4) + all 4 weight transposes (z=0..3); Wq pre-scaled
    prep<<<dim3(32, 32, 5), 256, 0, stream>>>(x, Wq, Wk, Wv, Wo, xb, WqkvT, WoT);

    // QKV = xb @ [Wq|Wk|Wv] : M=4096 N=3072 K=1024 (768 blocks = 3/CU);
    // V-tiles stored transposed straight to VT (transpose_v fused away)
    gemm_bt<false><<<dim3(3072 / 128, 4096 / 128), 256, 0, stream>>>(
        xb, WqkvT, QKV, 4096, 3072, 1024, VT);

    // attention -> att[bs][hc]; grid (bh, qt) so XCD = bh%8 (L2-local K/V)
    flash_attn<<<dim3(32, 16), 256, 0, stream>>>(QKV, VT, att);

    // out = att @ Wo : M=4096 N=1024 K=1024, fp32 out, 64x128 tile (2 blk/CU)
    gemm_tm2<<<dim3(1024 / 128, 4096 / 64), 256, 0, stream>>>(
        att, WoT, (float*)d_out, 4096, 1024, 1024);
}

// Round 6
// 174.554 us; speedup vs baseline: 1.5090x; 1.0003x over previous
//
#include <hip/hip_runtime.h>
#include <hip/hip_bf16.h>
#include <stdint.h>
#include <stddef.h>

// B=2, S=2048, D=1024, H=16, C=64
typedef __bf16 bf16;
typedef __bf16 bf16x4 __attribute__((ext_vector_type(4)));
typedef __bf16 bf16x8 __attribute__((ext_vector_type(8)));
typedef float f32x4 __attribute__((ext_vector_type(4)));

#define DEV __device__ __forceinline__

// async global->LDS, 16B per lane; LDS dest is wave-uniform base + lane*16
DEV void async16(const bf16* g, bf16* l) {
    __builtin_amdgcn_global_load_lds(
        (const __attribute__((address_space(1))) void*)g,
        (__attribute__((address_space(3))) void*)l,
        16, 0, 0);
}

// pack two f32 -> two bf16 (truncation) in ONE v_perm_b32.
// Truncation bias cancels in P/l since l is computed from the same packed P.
DEV uint32_t pktrunc(float lo, float hi) {
    return __builtin_amdgcn_perm(__builtin_bit_cast(uint32_t, hi),
                                 __builtin_bit_cast(uint32_t, lo), 0x07060302u);
}

// ---------------- prep: x->bf16 convert (z=4) + 4 weight transposes (z=0..3) --

__global__ void prep(const float* __restrict__ x,
                     const float* __restrict__ Wq, const float* __restrict__ Wk,
                     const float* __restrict__ Wv, const float* __restrict__ Wo,
                     bf16* __restrict__ xb, bf16* __restrict__ WqkvT,
                     bf16* __restrict__ WoT) {
    __shared__ float t[32][33];
    if (blockIdx.z == 4) {
        const int bid = blockIdx.y * 32 + blockIdx.x;
#pragma unroll
        for (int i = 0; i < 4; ++i) {
            const int idx = ((bid * 4 + i) * 256 + threadIdx.x) * 4;
            const float4 v = *(const float4*)(x + idx);
            bf16 o4[4] = {(bf16)v.x, (bf16)v.y, (bf16)v.z, (bf16)v.w};
            *(uint2*)(xb + idx) = *(const uint2*)o4;
        }
        return;
    }
    const float* src;
    bf16* dst;
    float scale = 1.0f;
    switch (blockIdx.z) {
        case 0: src = Wq; dst = WqkvT; scale = 0.125f * 1.4426950408889634f; break;
        case 1: src = Wk; dst = WqkvT + 1024 * 1024; break;
        case 2: src = Wv; dst = WqkvT + 2 * 1024 * 1024; break;
        default: src = Wo; dst = WoT; break;
    }
    const int c0 = blockIdx.x * 32, r0 = blockIdx.y * 32;
    const int tx = threadIdx.x & 31, ty = threadIdx.x >> 5;  // 32x8
#pragma unroll
    for (int i = 0; i < 32; i += 8)
        t[ty + i][tx] = src[(size_t)(r0 + ty + i) * 1024 + c0 + tx];
    __syncthreads();
#pragma unroll
    for (int i = 0; i < 32; i += 8)
        dst[(size_t)(c0 + ty + i) * 1024 + r0 + tx] = (bf16)(t[tx][ty + i] * scale);
}

// ---------------- GEMM (TM=4): C[m][n] = sum_k A[m][k] * BT[n][k] ----------
// 128x128 tile, BK=64 as two BK=32 panels. If VTout != nullptr, tiles with
// n0 >= 2048 are stored TRANSPOSED to VTout[n-2048][m] (bf16) instead of C.
// Epilogue: r0 scalar-store form (r4's LDS-staged variant measured +3us
// slower via cross-round delta accounting; reverted).

template <bool OUT_F32>
__global__ __launch_bounds__(256, 3) void gemm_bt(
    const bf16* __restrict__ A, const bf16* __restrict__ BT, void* __restrict__ Cout,
    int M, int N, int K, bf16* __restrict__ VTout) {
    __shared__ __attribute__((aligned(16))) bf16 As[2 * 128 * 32];
    __shared__ __attribute__((aligned(16))) bf16 Bs[2 * 128 * 32];
    const int tid = threadIdx.x;
    const int wid = tid >> 6;
    const int lane = tid & 63;
    const int quad = lane >> 4;
    const int l16 = lane & 15;
    const int wm = wid >> 1, wn = wid & 1;
    const int m0 = blockIdx.y * 128, n0 = blockIdx.x * 128;

    const int srow = wid * 32 + (lane >> 2);
    const int skcol = (lane & 3) * 8;
    const bf16* ag = A + (size_t)(m0 + srow) * K + skcol;
    const bf16* bg = BT + (size_t)(n0 + srow) * K + skcol;

    f32x4 acc[4][4];
#pragma unroll
    for (int i = 0; i < 4; ++i)
#pragma unroll
        for (int j = 0; j < 4; ++j) acc[i][j] = (f32x4){0.f, 0.f, 0.f, 0.f};

    for (int k0 = 0; k0 < K; k0 += 64) {
#pragma unroll
        for (int p = 0; p < 2; ++p) {
            async16(ag + k0 + p * 32, &As[p * 4096 + (wid * 32) * 32]);
            async16(ag + (size_t)16 * K + k0 + p * 32, &As[p * 4096 + (wid * 32 + 16) * 32]);
            async16(bg + k0 + p * 32, &Bs[p * 4096 + (wid * 32) * 32]);
            async16(bg + (size_t)16 * K + k0 + p * 32, &Bs[p * 4096 + (wid * 32 + 16) * 32]);
        }
        __syncthreads();

#pragma unroll
        for (int ks = 0; ks < 2; ++ks) {
            bf16x8 af[4], bfr[4];
#pragma unroll
            for (int mi = 0; mi < 4; ++mi)
                af[mi] = *(const bf16x8*)&As[ks * 4096 + (wm * 64 + mi * 16 + l16) * 32 + quad * 8];
#pragma unroll
            for (int ni = 0; ni < 4; ++ni)
                bfr[ni] = *(const bf16x8*)&Bs[ks * 4096 + (wn * 64 + ni * 16 + l16) * 32 + quad * 8];
#pragma unroll
            for (int mi = 0; mi < 4; ++mi)
#pragma unroll
                for (int ni = 0; ni < 4; ++ni)
                    acc[mi][ni] = __builtin_amdgcn_mfma_f32_16x16x32_bf16(
                        af[mi], bfr[ni], acc[mi][ni], 0, 0, 0);
        }
        __syncthreads();
    }

    if (VTout && n0 >= 2048) {
        // store transposed: VT[n-2048][m], pack 4 consecutive m (r) as 8B
#pragma unroll
        for (int mi = 0; mi < 4; ++mi)
#pragma unroll
            for (int ni = 0; ni < 4; ++ni) {
                bf16 pk[4] = {(bf16)acc[mi][ni][0], (bf16)acc[mi][ni][1],
                              (bf16)acc[mi][ni][2], (bf16)acc[mi][ni][3]};
                *(uint2*)&VTout[(size_t)(n0 - 2048 + wn * 64 + ni * 16 + l16) * 4096 +
                                (m0 + wm * 64 + mi * 16 + quad * 4)] = *(const uint2*)pk;
            }
        return;
    }
    if (OUT_F32) {
        float* C = (float*)Cout;
#pragma unroll
        for (int mi = 0; mi < 4; ++mi)
#pragma unroll
            for (int ni = 0; ni < 4; ++ni)
#pragma unroll
                for (int r = 0; r < 4; ++r)
                    C[(size_t)(m0 + wm * 64 + mi * 16 + quad * 4 + r) * N +
                      (n0 + wn * 64 + ni * 16 + l16)] = acc[mi][ni][r];
    } else {
        bf16* C = (bf16*)Cout;
#pragma unroll
        for (int mi = 0; mi < 4; ++mi)
#pragma unroll
            for (int ni = 0; ni < 4; ++ni)
#pragma unroll
                for (int r = 0; r < 4; ++r)
                    C[(size_t)(m0 + wm * 64 + mi * 16 + quad * 4 + r) * N +
                      (n0 + wn * 64 + ni * 16 + l16)] = (bf16)acc[mi][ni][r];
    }
}

// ---------------- GEMM (TM=2): 64x128 tile, fp32 out --------------------

__global__ __launch_bounds__(256, 4) void gemm_tm2(
    const bf16* __restrict__ A, const bf16* __restrict__ BT, float* __restrict__ C,
    int M, int N, int K) {
    __shared__ __attribute__((aligned(16))) bf16 As[2 * 64 * 32];
    __shared__ __attribute__((aligned(16))) bf16 Bs[2 * 128 * 32];
    const int tid = threadIdx.x;
    const int wid = tid >> 6;
    const int lane = tid & 63;
    const int quad = lane >> 4;
    const int l16 = lane & 15;
    const int wm = wid >> 1, wn = wid & 1;
    const int m0 = blockIdx.y * 64, n0 = blockIdx.x * 128;

    const int srowA = wid * 16 + (lane >> 2);
    const int srowB = wid * 32 + (lane >> 2);
    const int skcol = (lane & 3) * 8;
    const bf16* ag = A + (size_t)(m0 + srowA) * K + skcol;
    const bf16* bg = BT + (size_t)(n0 + srowB) * K + skcol;

    f32x4 acc[2][4];
#pragma unroll
    for (int i = 0; i < 2; ++i)
#pragma unroll
        for (int j = 0; j < 4; ++j) acc[i][j] = (f32x4){0.f, 0.f, 0.f, 0.f};

    for (int k0 = 0; k0 < K; k0 += 64) {
#pragma unroll
        for (int p = 0; p < 2; ++p) {
            async16(ag + k0 + p * 32, &As[p * 2048 + (wid * 16) * 32]);
            async16(bg + k0 + p * 32, &Bs[p * 4096 + (wid * 32) * 32]);
            async16(bg + (size_t)16 * K + k0 + p * 32, &Bs[p * 4096 + (wid * 32 + 16) * 32]);
        }
        __syncthreads();

#pragma unroll
        for (int ks = 0; ks < 2; ++ks) {
            bf16x8 af[2], bfr[4];
#pragma unroll
            for (int mi = 0; mi < 2; ++mi)
                af[mi] = *(const bf16x8*)&As[ks * 2048 + (wm * 32 + mi * 16 + l16) * 32 + quad * 8];
#pragma unroll
            for (int ni = 0; ni < 4; ++ni)
                bfr[ni] = *(const bf16x8*)&Bs[ks * 4096 + (wn * 64 + ni * 16 + l16) * 32 + quad * 8];
#pragma unroll
            for (int mi = 0; mi < 2; ++mi)
#pragma unroll
                for (int ni = 0; ni < 4; ++ni)
                    acc[mi][ni] = __builtin_amdgcn_mfma_f32_16x16x32_bf16(
                        af[mi], bfr[ni], acc[mi][ni], 0, 0, 0);
        }
        __syncthreads();
    }

#pragma unroll
    for (int mi = 0; mi < 2; ++mi)
#pragma unroll
        for (int ni = 0; ni < 4; ++ni)
#pragma unroll
            for (int r = 0; r < 4; ++r)
                C[(size_t)(m0 + wm * 32 + mi * 16 + quad * 4 + r) * N +
                  (n0 + wn * 64 + ni * 16 + l16)] = acc[mi][ni][r];
}

// ---------------- flash attention (v16 = v11 EXACT + T5 setprio) ----------
// Structure ledger: v12 (Q=64 dbuf) 58.7, v13 (512thr lockstep) 48.7,
// v14 (V-from-L2) 135.6, v15 (K/V dbuf 1-barrier) 64.2 -- every deviation
// from v11's 2-barrier lockstep lost. v16 (v11 + setprio): 45.76 MEASURED
// (T5 confirmed: -4.9%, conflicts 1.57M->1.05M). Do not restructure without
// a fully derived race-safe schedule.

__global__ __launch_bounds__(256, 2) void flash_attn(
    const bf16* __restrict__ QKV, const bf16* __restrict__ VT, bf16* __restrict__ att) {
    constexpr int LDK = 72;   // Ks stride: frag-read banks 4*(l16+quad) uniform
    constexpr int LDV = 136;  // Vs stride: b64 reads 2-way (free), writes 8-phase
    __shared__ __attribute__((aligned(16))) char smem[36864];
    bf16* Ks = (bf16*)smem;                // [128][72]  = 18432 B
    bf16* Vs = (bf16*)(smem + 18432);      // [64][136]  = 17408 B -> 35840
    float* Osc = (float*)smem;             // epilogue alias: 2 regions x 16 KB
    float* Lred = (float*)(smem + 32768);  // [4][64] floats

    const int tid = threadIdx.x, wid = tid >> 6, lane = tid & 63;
    const int quad = lane >> 4, l16 = lane & 15;
    const int qh = wid >> 1, kh = wid & 1;
    const int bh = blockIdx.x, qt = blockIdx.y;   // XCD = bh % 8 (L2-local K/V)
    const int b = bh >> 4, h = bh & 15;
    const int q0 = qt * 128;

    // ---- Q B-frags (resident): B[k=quad*8+j][n=l16] = Q[q][c] ----
    bf16x8 qf[4][2];
    {
        const bf16* qbase = QKV + (size_t)(b * 2048 + q0 + qh * 64 + l16) * 3072 + h * 64 + quad * 8;
#pragma unroll
        for (int mi = 0; mi < 4; ++mi)
#pragma unroll
            for (int ks = 0; ks < 2; ++ks)
                qf[mi][ks] = *(const bf16x8*)(qbase + (size_t)mi * 16 * 3072 + ks * 32);
    }

    // staging geometry (coalesced): K 128 rows x 128 B, V 64 rows x 256 B
    const int krow = tid >> 3, kcol = (tid & 7) * 8;   // 32 rows/pass, 4 passes
    const int vrow = tid >> 4, vcol = (tid & 15) * 8;  // 16 rows/pass, 4 passes
    const bf16* kg = QKV + (size_t)(b * 2048 + krow) * 3072 + 1024 + h * 64 + kcol;
    const bf16* vg = VT + (size_t)(h * 64 + vrow) * 4096 + b * 2048 + vcol;

    bf16x8 kr[4], vr[4];
#pragma unroll
    for (int p = 0; p < 4; ++p) {
        kr[p] = *(const bf16x8*)(kg + (size_t)(32 * p) * 3072);
        vr[p] = *(const bf16x8*)(vg + (size_t)(16 * p) * 4096);
    }

    const bf16 one = (bf16)1.0f;
    const bf16x8 onesf = (bf16x8){one, one, one, one, one, one, one, one};

    f32x4 o[4][4];
    f32x4 ls[4];
#pragma unroll
    for (int mi = 0; mi < 4; ++mi) {
        ls[mi] = (f32x4){0.f, 0.f, 0.f, 0.f};
#pragma unroll
        for (int ct = 0; ct < 4; ++ct) o[mi][ct] = (f32x4){0.f, 0.f, 0.f, 0.f};
    }

    for (int it = 0; it < 16; ++it) {
        // ---- stage prefetched regs -> LDS ----
#pragma unroll
        for (int p = 0; p < 4; ++p) {
            *(bf16x8*)&Ks[(32 * p + krow) * LDK + kcol] = kr[p];
            *(bf16x8*)&Vs[(16 * p + vrow) * LDV + vcol] = vr[p];
        }
        __syncthreads();

        // ---- prefetch next big-iter (hidden behind compute phase) ----
        if (it < 15) {
            const size_t ko = (size_t)(it + 1) * 128;
#pragma unroll
            for (int p = 0; p < 4; ++p) {
                kr[p] = *(const bf16x8*)(kg + (ko + 32 * p) * 3072);
                vr[p] = *(const bf16x8*)(vg + (size_t)(16 * p) * 4096 + ko);
            }
        }

        // ---- compute: wave's 64 keys as 2 pairs of 16-key groups ----
#pragma unroll
        for (int pr = 0; pr < 2; ++pr) {
            const int kb = kh * 64 + pr * 32;  // pair base (rel key)
            const bf16x8 kfA0 = *(const bf16x8*)&Ks[(kb + l16) * LDK + quad * 8];
            const bf16x8 kfA1 = *(const bf16x8*)&Ks[(kb + l16) * LDK + 32 + quad * 8];
            const bf16x8 kfB0 = *(const bf16x8*)&Ks[(kb + 16 + l16) * LDK + quad * 8];
            const bf16x8 kfB1 = *(const bf16x8*)&Ks[(kb + 16 + l16) * LDK + 32 + quad * 8];
            bf16x8 vf[4];
#pragma unroll
            for (int ct = 0; ct < 4; ++ct) {
                const bf16x4 lo = *(const bf16x4*)&Vs[(ct * 16 + l16) * LDV + kb + quad * 4];
                const bf16x4 hi = *(const bf16x4*)&Vs[(ct * 16 + l16) * LDV + kb + 16 + quad * 4];
                vf[ct] = (bf16x8){lo[0], lo[1], lo[2], lo[3], hi[0], hi[1], hi[2], hi[3]};
            }
            __builtin_amdgcn_s_setprio(1);
#pragma unroll
            for (int mi = 0; mi < 4; ++mi) {
                f32x4 sA = (f32x4){0.f, 0.f, 0.f, 0.f};
                f32x4 sB = (f32x4){0.f, 0.f, 0.f, 0.f};
                sA = __builtin_amdgcn_mfma_f32_16x16x32_bf16(kfA0, qf[mi][0], sA, 0, 0, 0);
                sA = __builtin_amdgcn_mfma_f32_16x16x32_bf16(kfA1, qf[mi][1], sA, 0, 0, 0);
                sB = __builtin_amdgcn_mfma_f32_16x16x32_bf16(kfB0, qf[mi][0], sB, 0, 0, 0);
                sB = __builtin_amdgcn_mfma_f32_16x16x32_bf16(kfB1, qf[mi][1], sB, 0, 0, 0);

                const float pa0 = __builtin_amdgcn_exp2f(sA[0]);
                const float pa1 = __builtin_amdgcn_exp2f(sA[1]);
                const float pa2 = __builtin_amdgcn_exp2f(sA[2]);
                const float pa3 = __builtin_amdgcn_exp2f(sA[3]);
                const float pb0 = __builtin_amdgcn_exp2f(sB[0]);
                const float pb1 = __builtin_amdgcn_exp2f(sB[1]);
                const float pb2 = __builtin_amdgcn_exp2f(sB[2]);
                const float pb3 = __builtin_amdgcn_exp2f(sB[3]);

                // P A-frag via truncation pack (4 v_perm); lane = P[q=l16][j0..7]
                union { uint32_t u[4]; bf16x8 v; } pu;
                pu.u[0] = pktrunc(pa0, pa1);
                pu.u[1] = pktrunc(pa2, pa3);
                pu.u[2] = pktrunc(pb0, pb1);
                pu.u[3] = pktrunc(pb2, pb3);
                const bf16x8 pf = pu.v;
#pragma unroll
                for (int ct = 0; ct < 4; ++ct)
                    o[mi][ct] = __builtin_amdgcn_mfma_f32_16x16x32_bf16(pf, vf[ct], o[mi][ct], 0, 0, 0);
                // l-sum on the matrix pipe: D[q][*] = sum_k pf (all cols equal)
                ls[mi] = __builtin_amdgcn_mfma_f32_16x16x32_bf16(pf, onesf, ls[mi], 0, 0, 0);
            }
            __builtin_amdgcn_s_setprio(0);
        }
        __syncthreads();
    }

    // ---- epilogue: publish l (already row-summed, q = mi*16+quad*4+r), ----
    // ---- cross-wave O reduce ----
    if (l16 == 0) {
#pragma unroll
        for (int mi = 0; mi < 4; ++mi)
#pragma unroll
            for (int r = 0; r < 4; ++r)
                Lred[wid * 64 + mi * 16 + quad * 4 + r] = ls[mi][r];
    }
    if (kh == 1) {
        float* dst = Osc + qh * 4096;
#pragma unroll
        for (int mi = 0; mi < 4; ++mi)
#pragma unroll
            for (int ct = 0; ct < 4; ++ct)
                *(f32x4*)(dst + (mi * 4 + ct) * 256 + lane * 4) = o[mi][ct];
    }
    __syncthreads();

    if (kh == 0) {
        const float* src = Osc + qh * 4096;
#pragma unroll
        for (int mi = 0; mi < 4; ++mi)
#pragma unroll
            for (int ct = 0; ct < 4; ++ct)
                o[mi][ct] += *(const f32x4*)(src + (mi * 4 + ct) * 256 + lane * 4);
#pragma unroll
        for (int mi = 0; mi < 4; ++mi)
#pragma unroll
            for (int r = 0; r < 4; ++r) {
                const int qrow = mi * 16 + quad * 4 + r;
                const float l = Lred[(qh * 2) * 64 + qrow] + Lred[(qh * 2 + 1) * 64 + qrow];
                const float inv = 1.0f / l;
                bf16* orow = att + (size_t)(b * 2048 + q0 + qh * 64 + qrow) * 1024 + h * 64 + l16;
#pragma unroll
                for (int ct = 0; ct < 4; ++ct)
                    orow[ct * 16] = (bf16)(o[mi][ct][r] * inv);
            }
    }
}

// ---------------- launch ----------------

extern "C" void kernel_launch(void* const* d_in, const int* in_sizes, int n_in,
                              void* d_out, int out_size, void* d_ws, size_t ws_size,
                              hipStream_t stream) {
    (void)in_sizes; (void)n_in; (void)out_size; (void)ws_size;
    const float* x  = (const float*)d_in[0];
    const float* Wq = (const float*)d_in[1];
    const float* Wk = (const float*)d_in[2];
    const float* Wv = (const float*)d_in[3];
    const float* Wo = (const float*)d_in[4];

    char* ws = (char*)d_ws;
    bf16* xb    = (bf16*)(ws);                             // 8 MB  [4096][1024]
    bf16* att   = xb;                                      // alias: xb dead after QKV GEMM
    bf16* WqkvT = (bf16*)(ws + (size_t)8  * 1024 * 1024);  // 6 MB [3072][1024]
    bf16* WoT   = (bf16*)(ws + (size_t)14 * 1024 * 1024);  // 2 MB [1024][1024]
    bf16* QKV   = (bf16*)(ws + (size_t)16 * 1024 * 1024);  // 24 MB [4096][3072] (V region unused)
    bf16* VT    = (bf16*)(ws + (size_t)40 * 1024 * 1024);  // 8 MB [1024][4096]
    // total 48 MB

    // x->bf16 (z=4) + all 4 weight transposes (z=0..3); Wq pre-scaled
    prep<<<dim3(32, 32, 5), 256, 0, stream>>>(x, Wq, Wk, Wv, Wo, xb, WqkvT, WoT);

    // QKV = xb @ [Wq|Wk|Wv] : M=4096 N=3072 K=1024 (768 blocks = 3/CU);
    // V-tiles stored transposed straight to VT (transpose_v fused away)
    gemm_bt<false><<<dim3(3072 / 128, 4096 / 128), 256, 0, stream>>>(
        xb, WqkvT, QKV, 4096, 3072, 1024, VT);

    // attention -> att[bs][hc]; grid (bh, qt) so XCD = bh%8 (L2-local K/V)
    flash_attn<<<dim3(32, 16), 256, 0, stream>>>(QKV, VT, att);

    // out = att @ Wo : M=4096 N=1024 K=1024, fp32 out, 64x128 tile (2 blk/CU)
    gemm_tm2<<<dim3(1024 / 128, 4096 / 64), 256, 0, stream>>>(
        att, WoT, (float*)d_out, 4096, 1024, 1024);
}